// Round 1
// baseline (1097.873 us; speedup 1.0000x reference)
//
#include <hip/hip_runtime.h>

typedef __bf16 bf16x8 __attribute__((ext_vector_type(8)));
typedef float f32x4 __attribute__((ext_vector_type(4)));
typedef unsigned short u16;
typedef unsigned int u32;

#define QSCALE 0.08838834764831845f  // 1/sqrt(128)

static __device__ __forceinline__ float bf2f(u16 u) {
  union { float f; u32 i; } x; x.i = ((u32)u) << 16; return x.f;
}
static __device__ __forceinline__ u16 f2bf(float f) {
  union { float f; u32 i; } x; x.f = f;
  u32 r = x.i + 0x7fffu + ((x.i >> 16) & 1u);
  return (u16)(r >> 16);
}

// ---------------- convert activations f32 -> bf16 ----------------
// hs 1024x3072 (786432 float4), ehs 512x3072 (393216), ip 16x2048 (8192)
__global__ __launch_bounds__(256) void k_conv_acts(
    const float* __restrict__ hs, const float* __restrict__ ehs, const float* __restrict__ iph,
    u16* __restrict__ hsb, u16* __restrict__ ehsb, u16* __restrict__ ipb)
{
  int i = blockIdx.x * 256 + threadIdx.x;
  const float* s; u16* d; int j;
  if (i < 786432)        { s = hs;  d = hsb;  j = i; }
  else if (i < 1179648)  { s = ehs; d = ehsb; j = i - 786432; }
  else                   { s = iph; d = ipb;  j = i - 1179648; }
  float4 v = ((const float4*)s)[j];
  uint2 o;
  o.x = (u32)f2bf(v.x) | ((u32)f2bf(v.y) << 16);
  o.y = (u32)f2bf(v.z) | ((u32)f2bf(v.w) << 16);
  ((uint2*)d)[j] = o;
}

// ---------------- f32 -> bf16 (attn output, 1536x3072 = 1179648 float4) ----------------
__global__ __launch_bounds__(256) void k_conv_attn(const float* __restrict__ a, u16* __restrict__ b)
{
  int i = blockIdx.x * 256 + threadIdx.x;
  float4 v = ((const float4*)a)[i];
  uint2 o;
  o.x = (u32)f2bf(v.x) | ((u32)f2bf(v.y) << 16);
  o.y = (u32)f2bf(v.z) | ((u32)f2bf(v.w) << 16);
  ((uint2*)b)[i] = o;
}

// ---------------- weight transpose+convert: src (K,3072) f32 -> dst (3072,K) bf16 ----------------
struct WT { const float* src; u16* dst; int K; };
struct WTPack { WT w[10]; };

__global__ __launch_bounds__(256) void k_transp_w(WTPack p)
{
  WT d = p.w[blockIdx.z];
  int K = d.K;
  int k0 = blockIdx.y * 64;
  if (k0 >= K) return;
  int n0 = blockIdx.x * 64;
  __shared__ u16 T[64 * 72];   // [n][k], stride 72 (144B rows, 16B-aligned)
  int tid = threadIdx.x;
  #pragma unroll
  for (int i = 0; i < 4; i++) {
    int idx = tid + i * 256;          // 1024 items: 64 k-rows x 16 float4
    int r = idx >> 4, ch = idx & 15;
    float4 v = *(const float4*)(d.src + (size_t)(k0 + r) * 3072 + n0 + ch * 4);
    T[(ch*4+0)*72 + r] = f2bf(v.x);
    T[(ch*4+1)*72 + r] = f2bf(v.y);
    T[(ch*4+2)*72 + r] = f2bf(v.z);
    T[(ch*4+3)*72 + r] = f2bf(v.w);
  }
  __syncthreads();
  #pragma unroll
  for (int i = 0; i < 2; i++) {
    int idx = tid + i * 256;          // 512 items: 64 n-rows x 8 uint4
    int r = idx >> 3, ch = idx & 7;
    uint4 v = *(const uint4*)(T + r * 72 + ch * 8);
    *(uint4*)(d.dst + (size_t)(n0 + r) * K + k0 + ch * 8) = v;
  }
}

// ---------------- GEMM: C(M,3072) = A(M,K) @ W(K,3072) + bias ; W given transposed (3072,K) bf16
// 128x128 tile, BK=32, 4 waves (each 64x64), mfma 16x16x32 bf16.
__global__ __launch_bounds__(256) void k_gemm(
    const u16* __restrict__ A, int M, int K,
    const u16* __restrict__ W0, const u16* __restrict__ W1, const u16* __restrict__ W2,
    const float* __restrict__ b0, const float* __restrict__ b1, const float* __restrict__ b2,
    void* C0, void* C1, void* C2, int out_f32)
{
  __shared__ u16 As[128 * 32];   // [m][k]
  __shared__ u16 Bs[128 * 32];   // [n][k]  (W^T rows)
  int tid = threadIdx.x;
  int mat = blockIdx.y / 24;
  int n0 = (blockIdx.y % 24) * 128;
  int m0 = blockIdx.x * 128;
  const u16* Wt = mat == 0 ? W0 : (mat == 1 ? W1 : W2);
  const float* bias = mat == 0 ? b0 : (mat == 1 ? b1 : b2);
  void* C = mat == 0 ? C0 : (mat == 1 ? C1 : C2);

  int w = tid >> 6, lane = tid & 63, l15 = lane & 15, quad = lane >> 4;
  int wm = (w >> 1) * 64, wn = (w & 1) * 64;
  f32x4 acc[4][4] = {};

  for (int k0 = 0; k0 < K; k0 += 32) {
    #pragma unroll
    for (int i = 0; i < 2; i++) {
      int idx = tid + i * 256;        // 512 uint4 per tile
      int r = idx >> 2, ch = idx & 3;
      uint4 va = make_uint4(0u, 0u, 0u, 0u);
      if (m0 + r < M) va = *(const uint4*)(A + (size_t)(m0 + r) * K + k0 + ch * 8);
      ((uint4*)As)[idx] = va;
      uint4 vb = *(const uint4*)(Wt + (size_t)(n0 + r) * K + k0 + ch * 8);
      ((uint4*)Bs)[idx] = vb;
    }
    __syncthreads();
    bf16x8 af[4], bfr[4];
    #pragma unroll
    for (int t = 0; t < 4; t++) {
      af[t]  = *(const bf16x8*)(As + (wm + t * 16 + l15) * 32 + quad * 8);
      bfr[t] = *(const bf16x8*)(Bs + (wn + t * 16 + l15) * 32 + quad * 8);
    }
    #pragma unroll
    for (int mt = 0; mt < 4; mt++)
      #pragma unroll
      for (int nt = 0; nt < 4; nt++)
        acc[mt][nt] = __builtin_amdgcn_mfma_f32_16x16x32_bf16(af[mt], bfr[nt], acc[mt][nt], 0, 0, 0);
    __syncthreads();
  }

  #pragma unroll
  for (int mt = 0; mt < 4; mt++) {
    int row = m0 + wm + mt * 16 + quad * 4;   // C-layout: row = quad*4 + reg
    #pragma unroll
    for (int nt = 0; nt < 4; nt++) {
      int col = n0 + wn + nt * 16 + l15;      // C-layout: col = lane&15
      float bv = bias[col];
      #pragma unroll
      for (int r = 0; r < 4; r++) {
        if (row + r < M) {
          float v = acc[mt][nt][r] + bv;
          if (out_f32) ((float*)C)[(size_t)(row + r) * 3072 + col] = v;
          else         ((u16*)C)[(size_t)(row + r) * 3072 + col] = f2bf(v);
        }
      }
    }
  }
}

// ---------------- pack Q/K: RMS + RoPE + scale, into head-major (24, S, 128) bf16 ----------------
// one wave per (t,h); units 0..36863 = main (t=u/24, h=u%24), 36864..37247 = ip-K (16x24)
__global__ __launch_bounds__(256) void k_pack_qk(
    const u16* __restrict__ q, const u16* __restrict__ k,     // (1024,3072) bf16
    const u16* __restrict__ eq, const u16* __restrict__ ek,   // (512,3072)
    const u16* __restrict__ ipk,                              // (16,3072)
    const float* __restrict__ cosr, const float* __restrict__ sinr, // (1536,128)
    const float* __restrict__ nq, const float* __restrict__ nk,
    const float* __restrict__ naq, const float* __restrict__ nak,
    const float* __restrict__ nipq, const float* __restrict__ nipk,
    u16* __restrict__ Qf, u16* __restrict__ Kf, u16* __restrict__ Qip, u16* __restrict__ Kip)
{
  int u = blockIdx.x * 4 + (threadIdx.x >> 6);
  int lane = threadIdx.x & 63;
  int d0 = lane * 2;
  if (u < 36864) {
    int t = u / 24, h = u % 24;
    bool txt = t < 512;
    const u16* qrow = txt ? eq + (size_t)t * 3072 : q + (size_t)(t - 512) * 3072;
    const u16* krow = txt ? ek + (size_t)t * 3072 : k + (size_t)(t - 512) * 3072;
    u32 qv = ((const u32*)(qrow + h * 128))[lane];
    u32 kv = ((const u32*)(krow + h * 128))[lane];
    float q0 = bf2f((u16)qv), q1 = bf2f((u16)(qv >> 16));
    float k0 = bf2f((u16)kv), k1 = bf2f((u16)(kv >> 16));
    float sq = q0 * q0 + q1 * q1, sk = k0 * k0 + k1 * k1;
    #pragma unroll
    for (int off = 32; off > 0; off >>= 1) {
      sq += __shfl_xor(sq, off, 64);
      sk += __shfl_xor(sk, off, 64);
    }
    float rq = rsqrtf(sq * (1.0f / 128.0f) + 1e-6f);
    float rk = rsqrtf(sk * (1.0f / 128.0f) + 1e-6f);
    const float* wq = txt ? naq : nq;
    const float* wk = txt ? nak : nk;
    float2 c = ((const float2*)(cosr + (size_t)t * 128))[lane];
    float2 s = ((const float2*)(sinr + (size_t)t * 128))[lane];
    float xq0 = q0 * rq * wq[d0] * QSCALE, xq1 = q1 * rq * wq[d0 + 1] * QSCALE;
    float xk0 = k0 * rk * wk[d0],          xk1 = k1 * rk * wk[d0 + 1];
    // rope pair (2i,2i+1): out0 = x0*c0 - x1*s0 ; out1 = x1*c1 + x0*s1
    u32 oq = (u32)f2bf(xq0 * c.x - xq1 * s.x) | ((u32)f2bf(xq1 * c.y + xq0 * s.y) << 16);
    u32 ok = (u32)f2bf(xk0 * c.x - xk1 * s.x) | ((u32)f2bf(xk1 * c.y + xk0 * s.y) << 16);
    ((u32*)(Qf + ((size_t)h * 1536 + t) * 128))[lane] = oq;
    ((u32*)(Kf + ((size_t)h * 1536 + t) * 128))[lane] = ok;
    if (!txt) {  // ip-query: same RMS denominator, norm_ip_q_w, no rope
      float y0 = q0 * rq * nipq[d0] * QSCALE, y1 = q1 * rq * nipq[d0 + 1] * QSCALE;
      u32 oy = (u32)f2bf(y0) | ((u32)f2bf(y1) << 16);
      ((u32*)(Qip + ((size_t)h * 1024 + (t - 512)) * 128))[lane] = oy;
    }
  } else {
    int u2 = u - 36864;
    if (u2 < 384) {
      int h = u2 >> 4, t = u2 & 15;
      u32 v = ((const u32*)(ipk + (size_t)t * 3072 + h * 128))[lane];
      float x0 = bf2f((u16)v), x1 = bf2f((u16)(v >> 16));
      float ss = x0 * x0 + x1 * x1;
      #pragma unroll
      for (int off = 32; off > 0; off >>= 1) ss += __shfl_xor(ss, off, 64);
      float rr = rsqrtf(ss * (1.0f / 128.0f) + 1e-6f);
      u32 o = (u32)f2bf(x0 * rr * nipk[d0]) | ((u32)f2bf(x1 * rr * nipk[d0 + 1]) << 16);
      ((u32*)(Kip + ((size_t)h * 16 + t) * 128))[lane] = o;
    }
  }
}

// ---------------- pack V transposed: Vt (24,128,1536), Vipt (24,128,16) ----------------
__global__ __launch_bounds__(256) void k_pack_v(
    const u16* __restrict__ v, const u16* __restrict__ ev, const u16* __restrict__ ipv,
    u16* __restrict__ Vt, u16* __restrict__ Vipt)
{
  __shared__ u16 T[64 * 72];  // [d][t]
  int h = blockIdx.x, y = blockIdx.y, tid = threadIdx.x;
  if (y < 48) {
    int tb = (y % 24) * 64, db = (y / 24) * 64;
    #pragma unroll
    for (int i = 0; i < 2; i++) {
      int idx = tid + i * 256;
      int r = idx >> 3, ch = idx & 7;     // r = t row (64), ch = d chunk (8 bf16)
      int t = tb + r;
      const u16* src = (t < 512) ? ev + (size_t)t * 3072 : v + (size_t)(t - 512) * 3072;
      uint4 val = *(const uint4*)(src + h * 128 + db + ch * 8);
      u16 tmp[8];
      *(uint4*)tmp = val;
      #pragma unroll
      for (int j = 0; j < 8; j++) T[(ch * 8 + j) * 72 + r] = tmp[j];
    }
    __syncthreads();
    #pragma unroll
    for (int i = 0; i < 2; i++) {
      int idx = tid + i * 256;
      int r = idx >> 3, ch = idx & 7;     // r = d row, ch = t chunk
      uint4 val = *(const uint4*)(T + r * 72 + ch * 8);
      *(uint4*)(Vt + ((size_t)h * 128 + db + r) * 1536 + tb + ch * 8) = val;
    }
  } else {
    if (tid < 128) {
      #pragma unroll
      for (int t = 0; t < 16; t++)
        Vipt[((size_t)h * 128 + tid) * 16 + t] = ipv[(size_t)t * 3072 + h * 128 + tid];
    }
  }
}

// ---------------- flash attention: Q(24,Sq,128), K(24,Skv,128), Vt(24,128,Skv) -> out f32 (seq,3072)
// block = 4 waves, each wave owns 16 q-rows; kv tiles of 32 keys.
__global__ __launch_bounds__(256) void k_attn(
    const u16* __restrict__ Q, const u16* __restrict__ Kf, const u16* __restrict__ Vt,
    float* __restrict__ out, int Sq, int Skv, int row_off, int accum)
{
  __shared__ u16 Ks[32 * 136];   // [key][d], padded stride 136
  __shared__ u16 VsT[128 * 32];  // [d][key]
  __shared__ u16 Ps[4 * 16 * 40];// per-wave P tile [16][32], stride 40
  int tid = threadIdx.x;
  int h = blockIdx.y;
  int w = tid >> 6, lane = tid & 63, l15 = lane & 15, quad = lane >> 4;
  int mb = blockIdx.x * 64 + w * 16;

  bf16x8 aq[4];
  {
    const u16* qb = Q + ((size_t)h * Sq + mb + l15) * 128 + quad * 8;
    #pragma unroll
    for (int c = 0; c < 4; c++) aq[c] = *(const bf16x8*)(qb + c * 32);
  }
  f32x4 o[8] = {};
  float ms[4], ls[4];
  #pragma unroll
  for (int r = 0; r < 4; r++) { ms[r] = -3.0e38f; ls[r] = 0.0f; }
  u16* myPs = Ps + w * 640;

  for (int kb = 0; kb < Skv; kb += 32) {
    #pragma unroll
    for (int i = 0; i < 2; i++) {
      int idx = tid + i * 256;
      int r = idx >> 4, ch = idx & 15;
      uint4 v = make_uint4(0u, 0u, 0u, 0u);
      if (kb + r < Skv) v = *(const uint4*)(Kf + ((size_t)h * Skv + kb + r) * 128 + ch * 8);
      *(uint4*)(Ks + r * 136 + ch * 8) = v;
    }
    #pragma unroll
    for (int i = 0; i < 2; i++) {
      int idx = tid + i * 256;
      int r = idx >> 2, ch = idx & 3;
      uint4 v = make_uint4(0u, 0u, 0u, 0u);
      if (kb + ch * 8 + 7 < Skv) v = *(const uint4*)(Vt + ((size_t)h * 128 + r) * Skv + kb + ch * 8);
      *(uint4*)(VsT + r * 32 + ch * 8) = v;
    }
    __syncthreads();

    f32x4 s0 = {0.f, 0.f, 0.f, 0.f}, s1 = {0.f, 0.f, 0.f, 0.f};
    #pragma unroll
    for (int c = 0; c < 4; c++) {
      bf16x8 bk0 = *(const bf16x8*)(Ks + (l15)      * 136 + c * 32 + quad * 8);
      bf16x8 bk1 = *(const bf16x8*)(Ks + (16 + l15) * 136 + c * 32 + quad * 8);
      s0 = __builtin_amdgcn_mfma_f32_16x16x32_bf16(aq[c], bk0, s0, 0, 0, 0);
      s1 = __builtin_amdgcn_mfma_f32_16x16x32_bf16(aq[c], bk1, s1, 0, 0, 0);
    }
    if (kb + l15 >= Skv)      { s0[0] = s0[1] = s0[2] = s0[3] = -1e30f; }
    if (kb + 16 + l15 >= Skv) { s1[0] = s1[1] = s1[2] = s1[3] = -1e30f; }

    float alpha[4];
    #pragma unroll
    for (int r = 0; r < 4; r++) {
      float mx = fmaxf(s0[r], s1[r]);
      mx = fmaxf(mx, __shfl_xor(mx, 1, 64));
      mx = fmaxf(mx, __shfl_xor(mx, 2, 64));
      mx = fmaxf(mx, __shfl_xor(mx, 4, 64));
      mx = fmaxf(mx, __shfl_xor(mx, 8, 64));
      float mn = fmaxf(ms[r], mx);
      alpha[r] = __expf(ms[r] - mn);
      float p0 = __expf(s0[r] - mn);
      float p1 = __expf(s1[r] - mn);
      myPs[(quad * 4 + r) * 40 + l15]      = f2bf(p0);
      myPs[(quad * 4 + r) * 40 + 16 + l15] = f2bf(p1);
      float rs = p0 + p1;
      rs += __shfl_xor(rs, 1, 64);
      rs += __shfl_xor(rs, 2, 64);
      rs += __shfl_xor(rs, 4, 64);
      rs += __shfl_xor(rs, 8, 64);
      ls[r] = ls[r] * alpha[r] + rs;
      ms[r] = mn;
    }
    #pragma unroll
    for (int n = 0; n < 8; n++) {
      o[n][0] *= alpha[0]; o[n][1] *= alpha[1]; o[n][2] *= alpha[2]; o[n][3] *= alpha[3];
    }
    __asm__ volatile("s_waitcnt lgkmcnt(0)" ::: "memory");
    bf16x8 pa = *(const bf16x8*)(myPs + l15 * 40 + quad * 8);   // P in A-layout
    #pragma unroll
    for (int n = 0; n < 8; n++) {
      bf16x8 bv = *(const bf16x8*)(VsT + (n * 16 + l15) * 32 + quad * 8);
      o[n] = __builtin_amdgcn_mfma_f32_16x16x32_bf16(pa, bv, o[n], 0, 0, 0);
    }
    __syncthreads();
  }

  #pragma unroll
  for (int r = 0; r < 4; r++) {
    int t = mb + quad * 4 + r;
    float inv = 1.0f / ls[r];
    size_t base = (size_t)(row_off + t) * 3072 + h * 128 + l15;
    #pragma unroll
    for (int n = 0; n < 8; n++) {
      float v = o[n][r] * inv;
      if (accum) out[base + n * 16] += v;
      else       out[base + n * 16] = v;
    }
  }
}

extern "C" void kernel_launch(void* const* d_in, const int* in_sizes, int n_in,
                              void* d_out, int out_size, void* d_ws, size_t ws_size,
                              hipStream_t stream) {
  const float* hs   = (const float*)d_in[0];
  const float* ehs  = (const float*)d_in[1];
  const float* iph  = (const float*)d_in[2];
  const float* cosr = (const float*)d_in[3];
  const float* sinr = (const float*)d_in[4];
  const float* Wq   = (const float*)d_in[5];  const float* bq   = (const float*)d_in[6];
  const float* Wk   = (const float*)d_in[7];  const float* bk   = (const float*)d_in[8];
  const float* Wv   = (const float*)d_in[9];  const float* bv   = (const float*)d_in[10];
  const float* nq   = (const float*)d_in[11]; const float* nk   = (const float*)d_in[12];
  const float* Waq  = (const float*)d_in[13]; const float* baq  = (const float*)d_in[14];
  const float* Wak  = (const float*)d_in[15]; const float* bak  = (const float*)d_in[16];
  const float* Wav  = (const float*)d_in[17]; const float* bav  = (const float*)d_in[18];
  const float* naq  = (const float*)d_in[19]; const float* nak  = (const float*)d_in[20];
  const float* Wo   = (const float*)d_in[21]; const float* bo   = (const float*)d_in[22];
  const float* Wad  = (const float*)d_in[23]; const float* bad  = (const float*)d_in[24];
  const float* Wkip = (const float*)d_in[25]; const float* bkip = (const float*)d_in[26];
  const float* Wvip = (const float*)d_in[27]; const float* bvip = (const float*)d_in[28];
  const float* nipq = (const float*)d_in[29]; const float* nipk = (const float*)d_in[30];
  (void)in_sizes; (void)n_in; (void)out_size; (void)ws_size;

  char* ws = (char*)d_ws;
  size_t off = 0;
  auto alloc = [&](size_t bytes) { size_t o = off; off += (bytes + 255) & ~(size_t)255; return o; };

  u16* hsb  = (u16*)(ws + alloc((size_t)1024 * 3072 * 2));
  u16* ehsb = (u16*)(ws + alloc((size_t)512 * 3072 * 2));
  u16* ipb  = (u16*)(ws + alloc((size_t)16 * 2048 * 2));
  u16* WT_[10];
  for (int i = 0; i < 10; i++) WT_[i] = (u16*)(ws + alloc((size_t)3072 * (i < 8 ? 3072 : 2048) * 2));
  u16* qb   = (u16*)(ws + alloc((size_t)1024 * 3072 * 2));
  u16* kb_  = (u16*)(ws + alloc((size_t)1024 * 3072 * 2));
  u16* vb   = (u16*)(ws + alloc((size_t)1024 * 3072 * 2));
  u16* eqb  = (u16*)(ws + alloc((size_t)512 * 3072 * 2));
  u16* ekb  = (u16*)(ws + alloc((size_t)512 * 3072 * 2));
  u16* evb  = (u16*)(ws + alloc((size_t)512 * 3072 * 2));
  u16* ipkb = (u16*)(ws + alloc((size_t)16 * 3072 * 2));
  u16* ipvb = (u16*)(ws + alloc((size_t)16 * 3072 * 2));
  u16* Qf   = (u16*)(ws + alloc((size_t)24 * 1536 * 128 * 2));
  u16* Kff  = (u16*)(ws + alloc((size_t)24 * 1536 * 128 * 2));
  u16* Vt   = (u16*)(ws + alloc((size_t)24 * 128 * 1536 * 2));
  u16* Qip  = (u16*)(ws + alloc((size_t)24 * 1024 * 128 * 2));
  u16* Kip  = (u16*)(ws + alloc((size_t)24 * 16 * 128 * 2));
  u16* Vipt = (u16*)(ws + alloc((size_t)24 * 128 * 16 * 2));
  float* attn = (float*)(ws + alloc((size_t)1536 * 3072 * 4));
  u16* attnb  = (u16*)(ws + alloc((size_t)1536 * 3072 * 2));

  k_conv_acts<<<4640, 256, 0, stream>>>(hs, ehs, iph, hsb, ehsb, ipb);

  WTPack p;
  const float* wsrc[10] = {Wq, Wk, Wv, Waq, Wak, Wav, Wo, Wad, Wkip, Wvip};
  for (int i = 0; i < 10; i++) { p.w[i].src = wsrc[i]; p.w[i].dst = WT_[i]; p.w[i].K = (i < 8 ? 3072 : 2048); }
  k_transp_w<<<dim3(48, 48, 10), 256, 0, stream>>>(p);

  // projections
  k_gemm<<<dim3(8, 72), 256, 0, stream>>>(hsb, 1024, 3072, WT_[0], WT_[1], WT_[2], bq, bk, bv, qb, kb_, vb, 0);
  k_gemm<<<dim3(4, 72), 256, 0, stream>>>(ehsb, 512, 3072, WT_[3], WT_[4], WT_[5], baq, bak, bav, eqb, ekb, evb, 0);
  k_gemm<<<dim3(1, 48), 256, 0, stream>>>(ipb, 16, 2048, WT_[8], WT_[9], WT_[9], bkip, bvip, bvip, ipkb, ipvb, ipvb, 0);

  // pack attention operands
  k_pack_qk<<<9312, 256, 0, stream>>>(qb, kb_, eqb, ekb, ipkb, cosr, sinr, nq, nk, naq, nak, nipq, nipk, Qf, Kff, Qip, Kip);
  k_pack_v<<<dim3(24, 49), 256, 0, stream>>>(vb, evb, ipvb, Vt, Vipt);

  // attention: main then ip (accumulates into rows 512..1535)
  k_attn<<<dim3(24, 24), 256, 0, stream>>>(Qf, Kff, Vt, attn, 1536, 1536, 0, 0);
  k_attn<<<dim3(16, 24), 256, 0, stream>>>(Qip, Kip, Vipt, attn, 1024, 16, 512, 1);

  k_conv_attn<<<4608, 256, 0, stream>>>(attn, attnb);

  // output projections straight into d_out (f32): img first, then enc
  float* out = (float*)d_out;
  k_gemm<<<dim3(8, 24), 256, 0, stream>>>(attnb + (size_t)512 * 3072, 1024, 3072,
      WT_[6], WT_[6], WT_[6], bo, bo, bo, out, out, out, 1);
  k_gemm<<<dim3(4, 24), 256, 0, stream>>>(attnb, 512, 3072,
      WT_[7], WT_[7], WT_[7], bad, bad, bad, out + (size_t)1024 * 3072, out + (size_t)1024 * 3072, out + (size_t)1024 * 3072, 1);
}

// Round 2
// 786.330 us; speedup vs baseline: 1.3962x; 1.3962x over previous
//
#include <hip/hip_runtime.h>

typedef __bf16 bf16x8 __attribute__((ext_vector_type(8)));
typedef float f32x4 __attribute__((ext_vector_type(4)));
typedef unsigned short u16;
typedef unsigned int u32;

#define QSCALE 0.08838834764831845f  // 1/sqrt(128)

static __device__ __forceinline__ float bf2f(u16 u) {
  union { float f; u32 i; } x; x.i = ((u32)u) << 16; return x.f;
}
static __device__ __forceinline__ u16 f2bf(float f) {
  union { float f; u32 i; } x; x.f = f;
  u32 r = x.i + 0x7fffu + ((x.i >> 16) & 1u);
  return (u16)(r >> 16);
}
// async global->LDS, 16B per lane; lds dest must be wave-uniform base (+lane*16 by HW)
static __device__ __forceinline__ void gload16(const void* gp, void* lp) {
  __builtin_amdgcn_global_load_lds(
      (const __attribute__((address_space(1))) u32*)gp,
      (__attribute__((address_space(3))) u32*)lp, 16, 0, 0);
}

// ---------------- convert activations f32 -> bf16 ----------------
__global__ __launch_bounds__(256) void k_conv_acts(
    const float* __restrict__ hs, const float* __restrict__ ehs, const float* __restrict__ iph,
    u16* __restrict__ hsb, u16* __restrict__ ehsb, u16* __restrict__ ipb)
{
  int i = blockIdx.x * 256 + threadIdx.x;
  const float* s; u16* d; int j;
  if (i < 786432)        { s = hs;  d = hsb;  j = i; }
  else if (i < 1179648)  { s = ehs; d = ehsb; j = i - 786432; }
  else                   { s = iph; d = ipb;  j = i - 1179648; }
  float4 v = ((const float4*)s)[j];
  uint2 o;
  o.x = (u32)f2bf(v.x) | ((u32)f2bf(v.y) << 16);
  o.y = (u32)f2bf(v.z) | ((u32)f2bf(v.w) << 16);
  ((uint2*)d)[j] = o;
}

// ---------------- weight transpose+convert: src (K,3072) f32 -> dst (3072,K) bf16 ----------------
struct WT { const float* src; u16* dst; int K; };
struct WTPack { WT w[10]; };

__global__ __launch_bounds__(256) void k_transp_w(WTPack p)
{
  WT d = p.w[blockIdx.z];
  int K = d.K;
  int k0 = blockIdx.y * 64;
  if (k0 >= K) return;
  int n0 = blockIdx.x * 64;
  __shared__ u16 T[64 * 72];
  int tid = threadIdx.x;
  #pragma unroll
  for (int i = 0; i < 4; i++) {
    int idx = tid + i * 256;
    int r = idx >> 4, ch = idx & 15;
    float4 v = *(const float4*)(d.src + (size_t)(k0 + r) * 3072 + n0 + ch * 4);
    T[(ch*4+0)*72 + r] = f2bf(v.x);
    T[(ch*4+1)*72 + r] = f2bf(v.y);
    T[(ch*4+2)*72 + r] = f2bf(v.z);
    T[(ch*4+3)*72 + r] = f2bf(v.w);
  }
  __syncthreads();
  #pragma unroll
  for (int i = 0; i < 2; i++) {
    int idx = tid + i * 256;
    int r = idx >> 3, ch = idx & 7;
    uint4 v = *(const uint4*)(T + r * 72 + ch * 8);
    *(uint4*)(d.dst + (size_t)(n0 + r) * K + k0 + ch * 8) = v;
  }
}

// ---------------- batched GEMM: per-job C(M,3072) = A(M,K) @ W^T + bias ----------------
// 128x128 tile, BK=32, 4 waves, global_load_lds staging (m97 structure).
struct GJob { const u16* A; const u16* W; const float* bias; void* C; int M; int K; int blk0; int out_f32; };
struct GPack { GJob j[8]; int njobs; };

__global__ __launch_bounds__(256) void k_gemm(GPack p)
{
  __shared__ u16 As[128 * 32];
  __shared__ u16 Bs[128 * 32];
  int bid = blockIdx.x;
  int ji = 0;
  while (ji + 1 < p.njobs && bid >= p.j[ji+1].blk0) ji++;
  GJob J = p.j[ji];
  int local = bid - J.blk0;
  int m0 = (local / 24) * 128;
  int n0 = (local % 24) * 128;

  int tid = threadIdx.x, w = tid >> 6, lane = tid & 63, l15 = lane & 15, quad = lane >> 4;
  int wm = (w >> 1) * 64, wn = (w & 1) * 64;
  f32x4 acc[4][4] = {};

  // staging: slot s in [0,512): row = s>>2, 16B chunk = s&3; A slots {tid, tid+256}, same for B
  int s0 = tid, s1 = tid + 256;
  const u16* Ag0 = J.A + (size_t)(m0 + (s0 >> 2)) * J.K + (s0 & 3) * 8;
  const u16* Ag1 = J.A + (size_t)(m0 + (s1 >> 2)) * J.K + (s1 & 3) * 8;
  const u16* Bg0 = J.W + (size_t)(n0 + (s0 >> 2)) * J.K + (s0 & 3) * 8;
  const u16* Bg1 = J.W + (size_t)(n0 + (s1 >> 2)) * J.K + (s1 & 3) * 8;
  u16* lA0 = As + w * 512;          // slot w*64 .. w*64+63  (u16 units: slot*8)
  u16* lA1 = As + 2048 + w * 512;   // slot 256+w*64 ..
  u16* lB0 = Bs + w * 512;
  u16* lB1 = Bs + 2048 + w * 512;

  for (int k0 = 0; k0 < J.K; k0 += 32) {
    gload16(Ag0 + k0, lA0);
    gload16(Ag1 + k0, lA1);
    gload16(Bg0 + k0, lB0);
    gload16(Bg1 + k0, lB1);
    __syncthreads();
    bf16x8 af[4], bfr[4];
    #pragma unroll
    for (int t = 0; t < 4; t++) {
      af[t]  = *(const bf16x8*)(As + (wm + t * 16 + l15) * 32 + quad * 8);
      bfr[t] = *(const bf16x8*)(Bs + (wn + t * 16 + l15) * 32 + quad * 8);
    }
    #pragma unroll
    for (int mt = 0; mt < 4; mt++)
      #pragma unroll
      for (int nt = 0; nt < 4; nt++)
        acc[mt][nt] = __builtin_amdgcn_mfma_f32_16x16x32_bf16(af[mt], bfr[nt], acc[mt][nt], 0, 0, 0);
    __syncthreads();
  }

  #pragma unroll
  for (int mt = 0; mt < 4; mt++) {
    int row = m0 + wm + mt * 16 + quad * 4;
    #pragma unroll
    for (int nt = 0; nt < 4; nt++) {
      int col = n0 + wn + nt * 16 + l15;
      float bv = J.bias[col];
      #pragma unroll
      for (int r = 0; r < 4; r++) {
        if (row + r < J.M) {
          float v = acc[mt][nt][r] + bv;
          if (J.out_f32) ((float*)J.C)[(size_t)(row + r) * 3072 + col] = v;
          else           ((u16*)J.C)[(size_t)(row + r) * 3072 + col] = f2bf(v);
        }
      }
    }
  }
}

// ---------------- pack Q/K: RMS + RoPE + scale, head-major ----------------
__global__ __launch_bounds__(256) void k_pack_qk(
    const u16* __restrict__ q, const u16* __restrict__ k,
    const u16* __restrict__ eq, const u16* __restrict__ ek,
    const u16* __restrict__ ipk,
    const float* __restrict__ cosr, const float* __restrict__ sinr,
    const float* __restrict__ nq, const float* __restrict__ nk,
    const float* __restrict__ naq, const float* __restrict__ nak,
    const float* __restrict__ nipq, const float* __restrict__ nipk,
    u16* __restrict__ Qf, u16* __restrict__ Kf, u16* __restrict__ Qip, u16* __restrict__ Kip)
{
  int u = blockIdx.x * 4 + (threadIdx.x >> 6);
  int lane = threadIdx.x & 63;
  int d0 = lane * 2;
  if (u < 36864) {
    int t = u / 24, h = u % 24;
    bool txt = t < 512;
    const u16* qrow = txt ? eq + (size_t)t * 3072 : q + (size_t)(t - 512) * 3072;
    const u16* krow = txt ? ek + (size_t)t * 3072 : k + (size_t)(t - 512) * 3072;
    u32 qv = ((const u32*)(qrow + h * 128))[lane];
    u32 kv = ((const u32*)(krow + h * 128))[lane];
    float q0 = bf2f((u16)qv), q1 = bf2f((u16)(qv >> 16));
    float k0 = bf2f((u16)kv), k1 = bf2f((u16)(kv >> 16));
    float sq = q0 * q0 + q1 * q1, sk = k0 * k0 + k1 * k1;
    #pragma unroll
    for (int off = 32; off > 0; off >>= 1) {
      sq += __shfl_xor(sq, off, 64);
      sk += __shfl_xor(sk, off, 64);
    }
    float rq = rsqrtf(sq * (1.0f / 128.0f) + 1e-6f);
    float rk = rsqrtf(sk * (1.0f / 128.0f) + 1e-6f);
    const float* wq = txt ? naq : nq;
    const float* wk = txt ? nak : nk;
    float2 c = ((const float2*)(cosr + (size_t)t * 128))[lane];
    float2 s = ((const float2*)(sinr + (size_t)t * 128))[lane];
    float xq0 = q0 * rq * wq[d0] * QSCALE, xq1 = q1 * rq * wq[d0 + 1] * QSCALE;
    float xk0 = k0 * rk * wk[d0],          xk1 = k1 * rk * wk[d0 + 1];
    u32 oq = (u32)f2bf(xq0 * c.x - xq1 * s.x) | ((u32)f2bf(xq1 * c.y + xq0 * s.y) << 16);
    u32 ok = (u32)f2bf(xk0 * c.x - xk1 * s.x) | ((u32)f2bf(xk1 * c.y + xk0 * s.y) << 16);
    ((u32*)(Qf + ((size_t)h * 1536 + t) * 128))[lane] = oq;
    ((u32*)(Kf + ((size_t)h * 1536 + t) * 128))[lane] = ok;
    if (!txt) {
      float y0 = q0 * rq * nipq[d0] * QSCALE, y1 = q1 * rq * nipq[d0 + 1] * QSCALE;
      u32 oy = (u32)f2bf(y0) | ((u32)f2bf(y1) << 16);
      ((u32*)(Qip + ((size_t)h * 1024 + (t - 512)) * 128))[lane] = oy;
    }
  } else {
    int u2 = u - 36864;
    if (u2 < 384) {
      int h = u2 >> 4, t = u2 & 15;
      u32 v = ((const u32*)(ipk + (size_t)t * 3072 + h * 128))[lane];
      float x0 = bf2f((u16)v), x1 = bf2f((u16)(v >> 16));
      float ss = x0 * x0 + x1 * x1;
      #pragma unroll
      for (int off = 32; off > 0; off >>= 1) ss += __shfl_xor(ss, off, 64);
      float rr = rsqrtf(ss * (1.0f / 128.0f) + 1e-6f);
      u32 o = (u32)f2bf(x0 * rr * nipk[d0]) | ((u32)f2bf(x1 * rr * nipk[d0 + 1]) << 16);
      ((u32*)(Kip + ((size_t)h * 64 + t) * 128))[lane] = o;   // Kip padded to 64 keys
    }
  }
}

// ---------------- pack V transposed: Vt (24,128,1536), Vipt (24,128,64) zero-padded ----------------
__global__ __launch_bounds__(256) void k_pack_v(
    const u16* __restrict__ v, const u16* __restrict__ ev, const u16* __restrict__ ipv,
    u16* __restrict__ Vt, u16* __restrict__ Vipt)
{
  __shared__ u16 T[64 * 72];
  int h = blockIdx.x, y = blockIdx.y, tid = threadIdx.x;
  if (y < 48) {
    int tb = (y % 24) * 64, db = (y / 24) * 64;
    #pragma unroll
    for (int i = 0; i < 2; i++) {
      int idx = tid + i * 256;
      int r = idx >> 3, ch = idx & 7;
      int t = tb + r;
      const u16* src = (t < 512) ? ev + (size_t)t * 3072 : v + (size_t)(t - 512) * 3072;
      uint4 val = *(const uint4*)(src + h * 128 + db + ch * 8);
      u16 tmp[8];
      *(uint4*)tmp = val;
      #pragma unroll
      for (int j = 0; j < 8; j++) T[(ch * 8 + j) * 72 + r] = tmp[j];
    }
    __syncthreads();
    #pragma unroll
    for (int i = 0; i < 2; i++) {
      int idx = tid + i * 256;
      int r = idx >> 3, ch = idx & 7;
      uint4 val = *(const uint4*)(T + r * 72 + ch * 8);
      *(uint4*)(Vt + ((size_t)h * 128 + db + r) * 1536 + tb + ch * 8) = val;
    }
  } else {
    if (tid < 128) {
      #pragma unroll
      for (int t = 0; t < 64; t++) {
        u16 val = 0;
        if (t < 16) val = ipv[(size_t)t * 3072 + h * 128 + tid];
        Vipt[((size_t)h * 128 + tid) * 64 + t] = val;  // zero pad keys 16..63
      }
    }
  }
}

// ---------------- flash attention, transposed-score formulation ----------------
// Q(24,Sq,128), K(24,Skv,128), V=V^T(24,128,Skv); 64-key tiles; 4 waves x 16 q-rows.
// S^T = K·Q^T via mfma(A=K, B=Q): row=key (quad*4+reg), col=q (lane&15) -> cheap column softmax.
// mode 0: write f32 to out. mode 1: write bf16, adding addend (ip_out) for rows >= 512.
__global__ __launch_bounds__(256) void k_attn(
    const u16* __restrict__ Q, const u16* __restrict__ K, const u16* __restrict__ V,
    const float* __restrict__ addend, void* __restrict__ out,
    int Sq, int Skv, int Skv_valid, int mode)
{
  __shared__ u16 Ks[64 * 128];   // [key][d-chunk swizzled]: chunk' = ch ^ (key&15)
  __shared__ u16 Vs[128 * 64];   // [d][key-chunk swizzled]: chunk' = ch ^ (d&7)
  __shared__ u16 Ps[4 * 16 * 68];
  int tid = threadIdx.x, h = blockIdx.y;
  int w = tid >> 6, lane = tid & 63, l15 = lane & 15, quad = lane >> 4;
  int mb = blockIdx.x * 64 + w * 16;

  bf16x8 aq[4];
  {
    const u16* qp = Q + ((size_t)h * Sq + mb + l15) * 128 + quad * 8;
    #pragma unroll
    for (int c = 0; c < 4; c++) aq[c] = *(const bf16x8*)(qp + c * 32);
  }

  const u16* Kg[4]; const u16* Vg[4];
  #pragma unroll
  for (int i = 0; i < 4; i++) {
    int s = tid + i * 256;
    int key = s >> 4, kc = (s & 15) ^ (key & 15);
    Kg[i] = K + ((size_t)h * Skv + key) * 128 + kc * 8;
    int d = s >> 3, vc = (s & 7) ^ (d & 7);
    Vg[i] = V + ((size_t)h * 128 + d) * Skv + vc * 8;
  }

  f32x4 o[8] = {};
  float m_col = -3.0e38f, l_col = 0.0f;
  u16* myPs = Ps + w * (16 * 68);

  for (int kb = 0; kb < Skv; kb += 64) {
    #pragma unroll
    for (int i = 0; i < 4; i++) {
      gload16(Kg[i] + (size_t)kb * 128, Ks + (i * 256 + w * 64) * 8);
      gload16(Vg[i] + kb,               Vs + (i * 256 + w * 64) * 8);
    }
    __syncthreads();

    f32x4 sc[4];
    #pragma unroll
    for (int mt = 0; mt < 4; mt++) {
      f32x4 a = {0.f, 0.f, 0.f, 0.f};
      int key = mt * 16 + l15;
      #pragma unroll
      for (int c = 0; c < 4; c++) {
        bf16x8 kf = *(const bf16x8*)(Ks + key * 128 + (((c * 4 + quad) ^ l15) * 8));
        a = __builtin_amdgcn_mfma_f32_16x16x32_bf16(kf, aq[c], a, 0, 0, 0);
      }
      sc[mt] = a;
    }
    if (Skv_valid != Skv) {
      #pragma unroll
      for (int mt = 0; mt < 4; mt++)
        #pragma unroll
        for (int r = 0; r < 4; r++)
          if (kb + mt * 16 + quad * 4 + r >= Skv_valid) sc[mt][r] = -1e30f;
    }

    float mx = sc[0][0];
    #pragma unroll
    for (int mt = 0; mt < 4; mt++)
      #pragma unroll
      for (int r = 0; r < 4; r++) mx = fmaxf(mx, sc[mt][r]);
    mx = fmaxf(mx, __shfl_xor(mx, 16, 64));
    mx = fmaxf(mx, __shfl_xor(mx, 32, 64));
    float mn = fmaxf(m_col, mx);
    float alpha = __expf(m_col - mn);
    m_col = mn;

    float sum = 0.f;
    #pragma unroll
    for (int mt = 0; mt < 4; mt++) {
      u16 pk[4];
      #pragma unroll
      for (int r = 0; r < 4; r++) {
        float pp = __expf(sc[mt][r] - mn);
        sum += pp;
        pk[r] = f2bf(pp);
      }
      uint2 pv;
      pv.x = (u32)pk[0] | ((u32)pk[1] << 16);
      pv.y = (u32)pk[2] | ((u32)pk[3] << 16);
      *(uint2*)(myPs + l15 * 68 + mt * 16 + quad * 4) = pv;
    }
    sum += __shfl_xor(sum, 16, 64);
    sum += __shfl_xor(sum, 32, 64);
    l_col = l_col * alpha + sum;

    float ar[4];
    #pragma unroll
    for (int r = 0; r < 4; r++) ar[r] = __shfl(alpha, quad * 4 + r, 64);
    #pragma unroll
    for (int nt = 0; nt < 8; nt++) {
      o[nt][0] *= ar[0]; o[nt][1] *= ar[1]; o[nt][2] *= ar[2]; o[nt][3] *= ar[3];
    }

    __asm__ volatile("s_waitcnt lgkmcnt(0)" ::: "memory");
    #pragma unroll
    for (int kc = 0; kc < 2; kc++) {
      bf16x8 pa = *(const bf16x8*)(myPs + l15 * 68 + kc * 32 + quad * 8);
      #pragma unroll
      for (int nt = 0; nt < 8; nt++) {
        int d = nt * 16 + l15;
        bf16x8 vf = *(const bf16x8*)(Vs + d * 64 + (((kc * 4 + quad) ^ (d & 7)) * 8));
        o[nt] = __builtin_amdgcn_mfma_f32_16x16x32_bf16(pa, vf, o[nt], 0, 0, 0);
      }
    }
    __syncthreads();
  }

  float linv = 1.0f / l_col;
  float lr[4];
  #pragma unroll
  for (int r = 0; r < 4; r++) lr[r] = __shfl(linv, quad * 4 + r, 64);
  #pragma unroll
  for (int r = 0; r < 4; r++) {
    int t = mb + quad * 4 + r;
    size_t base = (size_t)t * 3072 + h * 128 + l15;
    if (mode == 0) {
      float* O = (float*)out;
      #pragma unroll
      for (int nt = 0; nt < 8; nt++) O[base + nt * 16] = o[nt][r] * lr[r];
    } else {
      u16* O = (u16*)out;
      #pragma unroll
      for (int nt = 0; nt < 8; nt++) {
        float vv = o[nt][r] * lr[r];
        if (t >= 512) vv += addend[(size_t)(t - 512) * 3072 + h * 128 + nt * 16 + l15];
        O[base + nt * 16] = f2bf(vv);
      }
    }
  }
}

extern "C" void kernel_launch(void* const* d_in, const int* in_sizes, int n_in,
                              void* d_out, int out_size, void* d_ws, size_t ws_size,
                              hipStream_t stream) {
  const float* hs   = (const float*)d_in[0];
  const float* ehs  = (const float*)d_in[1];
  const float* iph  = (const float*)d_in[2];
  const float* cosr = (const float*)d_in[3];
  const float* sinr = (const float*)d_in[4];
  const float* Wq   = (const float*)d_in[5];  const float* bq   = (const float*)d_in[6];
  const float* Wk   = (const float*)d_in[7];  const float* bk   = (const float*)d_in[8];
  const float* Wv   = (const float*)d_in[9];  const float* bv   = (const float*)d_in[10];
  const float* nq   = (const float*)d_in[11]; const float* nk   = (const float*)d_in[12];
  const float* Waq  = (const float*)d_in[13]; const float* baq  = (const float*)d_in[14];
  const float* Wak  = (const float*)d_in[15]; const float* bak  = (const float*)d_in[16];
  const float* Wav  = (const float*)d_in[17]; const float* bav  = (const float*)d_in[18];
  const float* naq  = (const float*)d_in[19]; const float* nak  = (const float*)d_in[20];
  const float* Wo   = (const float*)d_in[21]; const float* bo   = (const float*)d_in[22];
  const float* Wad  = (const float*)d_in[23]; const float* bad  = (const float*)d_in[24];
  const float* Wkip = (const float*)d_in[25]; const float* bkip = (const float*)d_in[26];
  const float* Wvip = (const float*)d_in[27]; const float* bvip = (const float*)d_in[28];
  const float* nipq = (const float*)d_in[29]; const float* nipk = (const float*)d_in[30];
  (void)in_sizes; (void)n_in; (void)out_size; (void)ws_size;

  char* ws = (char*)d_ws;
  size_t off = 0;
  auto alloc = [&](size_t bytes) { size_t o = off; off += (bytes + 255) & ~(size_t)255; return o; };

  u16* hsb  = (u16*)(ws + alloc((size_t)1024 * 3072 * 2));
  u16* ehsb = (u16*)(ws + alloc((size_t)512 * 3072 * 2));
  u16* ipb  = (u16*)(ws + alloc((size_t)16 * 2048 * 2));
  u16* WT_[10];
  for (int i = 0; i < 10; i++) WT_[i] = (u16*)(ws + alloc((size_t)3072 * (i < 8 ? 3072 : 2048) * 2));
  u16* qb   = (u16*)(ws + alloc((size_t)1024 * 3072 * 2));
  u16* kb_  = (u16*)(ws + alloc((size_t)1024 * 3072 * 2));
  u16* vb   = (u16*)(ws + alloc((size_t)1024 * 3072 * 2));
  u16* eqb  = (u16*)(ws + alloc((size_t)512 * 3072 * 2));
  u16* ekb  = (u16*)(ws + alloc((size_t)512 * 3072 * 2));
  u16* evb  = (u16*)(ws + alloc((size_t)512 * 3072 * 2));
  u16* ipkb = (u16*)(ws + alloc((size_t)16 * 3072 * 2));
  u16* ipvb = (u16*)(ws + alloc((size_t)16 * 3072 * 2));
  u16* Qf   = (u16*)(ws + alloc((size_t)24 * 1536 * 128 * 2));
  u16* Kff  = (u16*)(ws + alloc((size_t)24 * 1536 * 128 * 2));
  u16* Vt   = (u16*)(ws + alloc((size_t)24 * 128 * 1536 * 2));
  u16* Qip  = (u16*)(ws + alloc((size_t)24 * 1024 * 128 * 2));
  u16* Kip  = (u16*)(ws + alloc((size_t)24 * 64 * 128 * 2));
  u16* Vipt = (u16*)(ws + alloc((size_t)24 * 128 * 64 * 2));
  float* ip_out = (float*)(ws + alloc((size_t)1024 * 3072 * 4));
  u16* attnb = (u16*)(ws + alloc((size_t)1536 * 3072 * 2));

  k_conv_acts<<<4640, 256, 0, stream>>>(hs, ehs, iph, hsb, ehsb, ipb);

  WTPack p;
  const float* wsrc[10] = {Wq, Wk, Wv, Waq, Wak, Wav, Wo, Wad, Wkip, Wvip};
  for (int i = 0; i < 10; i++) { p.w[i].src = wsrc[i]; p.w[i].dst = WT_[i]; p.w[i].K = (i < 8 ? 3072 : 2048); }
  k_transp_w<<<dim3(48, 48, 10), 256, 0, stream>>>(p);

  // all 8 projection GEMMs in one dispatch
  {
    GPack pp;
    const u16* As_[8]  = {hsb, hsb, hsb, ehsb, ehsb, ehsb, ipb, ipb};
    const u16* Ws_[8]  = {WT_[0], WT_[1], WT_[2], WT_[3], WT_[4], WT_[5], WT_[8], WT_[9]};
    const float* bs_[8] = {bq, bk, bv, baq, bak, bav, bkip, bvip};
    u16* Cs_[8]        = {qb, kb_, vb, eqb, ekb, evb, ipkb, ipvb};
    int Ms_[8] = {1024, 1024, 1024, 512, 512, 512, 16, 16};
    int Ks_[8] = {3072, 3072, 3072, 3072, 3072, 3072, 2048, 2048};
    int blk = 0;
    for (int i = 0; i < 8; i++) {
      pp.j[i].A = As_[i]; pp.j[i].W = Ws_[i]; pp.j[i].bias = bs_[i]; pp.j[i].C = Cs_[i];
      pp.j[i].M = Ms_[i]; pp.j[i].K = Ks_[i]; pp.j[i].blk0 = blk; pp.j[i].out_f32 = 0;
      blk += ((Ms_[i] + 127) / 128) * 24;
    }
    pp.njobs = 8;
    k_gemm<<<dim3(blk), 256, 0, stream>>>(pp);  // 912 blocks
  }

  k_pack_qk<<<9312, 256, 0, stream>>>(qb, kb_, eqb, ekb, ipkb, cosr, sinr, nq, nk, naq, nak, nipq, nipk, Qf, Kff, Qip, Kip);
  k_pack_v<<<dim3(24, 49), 256, 0, stream>>>(vb, evb, ipvb, Vt, Vipt);

  // IP attention first (f32), then main attention fuses the add and writes bf16
  k_attn<<<dim3(16, 24), 256, 0, stream>>>(Qip, Kip, Vipt, (const float*)nullptr, ip_out, 1024, 64, 16, 0);
  k_attn<<<dim3(24, 24), 256, 0, stream>>>(Qf, Kff, Vt, ip_out, attnb, 1536, 1536, 1536, 1);

  // output projections (2 jobs, one dispatch) straight into d_out f32
  {
    GPack pp;
    float* out = (float*)d_out;
    pp.j[0].A = attnb + (size_t)512 * 3072; pp.j[0].W = WT_[6]; pp.j[0].bias = bo;
    pp.j[0].C = out; pp.j[0].M = 1024; pp.j[0].K = 3072; pp.j[0].blk0 = 0; pp.j[0].out_f32 = 1;
    pp.j[1].A = attnb; pp.j[1].W = WT_[7]; pp.j[1].bias = bad;
    pp.j[1].C = out + (size_t)1024 * 3072; pp.j[1].M = 512; pp.j[1].K = 3072; pp.j[1].blk0 = 192; pp.j[1].out_f32 = 1;
    pp.njobs = 2;
    k_gemm<<<dim3(288), 256, 0, stream>>>(pp);
  }
}

// Round 3
// 728.476 us; speedup vs baseline: 1.5071x; 1.0794x over previous
//
#include <hip/hip_runtime.h>

typedef __bf16 bf16x8 __attribute__((ext_vector_type(8)));
typedef float f32x4 __attribute__((ext_vector_type(4)));
typedef unsigned short u16;
typedef unsigned int u32;

#define QSCALE 0.08838834764831845f  // 1/sqrt(128)

static __device__ __forceinline__ float bf2f(u16 u) {
  union { float f; u32 i; } x; x.i = ((u32)u) << 16; return x.f;
}
static __device__ __forceinline__ u16 f2bf(float f) {
  union { float f; u32 i; } x; x.f = f;
  u32 r = x.i + 0x7fffu + ((x.i >> 16) & 1u);
  return (u16)(r >> 16);
}
// async global->LDS, 16B per lane; lds dest must be wave-uniform base (+lane*16 by HW)
static __device__ __forceinline__ void gload16(const void* gp, void* lp) {
  __builtin_amdgcn_global_load_lds(
      (const __attribute__((address_space(1))) u32*)gp,
      (__attribute__((address_space(3))) u32*)lp, 16, 0, 0);
}

// ---------------- convert activations f32 -> bf16 ----------------
__global__ __launch_bounds__(256) void k_conv_acts(
    const float* __restrict__ hs, const float* __restrict__ ehs, const float* __restrict__ iph,
    u16* __restrict__ hsb, u16* __restrict__ ehsb, u16* __restrict__ ipb)
{
  int i = blockIdx.x * 256 + threadIdx.x;
  const float* s; u16* d; int j;
  if (i < 786432)        { s = hs;  d = hsb;  j = i; }
  else if (i < 1179648)  { s = ehs; d = ehsb; j = i - 786432; }
  else                   { s = iph; d = ipb;  j = i - 1179648; }
  float4 v = ((const float4*)s)[j];
  uint2 o;
  o.x = (u32)f2bf(v.x) | ((u32)f2bf(v.y) << 16);
  o.y = (u32)f2bf(v.z) | ((u32)f2bf(v.w) << 16);
  ((uint2*)d)[j] = o;
}

// ---------------- weight transpose+convert: src (K,3072) f32 -> dst (3072,K) bf16 ----------------
struct WT { const float* src; u16* dst; int K; };
struct WTPack { WT w[10]; };

__global__ __launch_bounds__(256) void k_transp_w(WTPack p)
{
  WT d = p.w[blockIdx.z];
  int K = d.K;
  int k0 = blockIdx.y * 64;
  if (k0 >= K) return;
  int n0 = blockIdx.x * 64;
  __shared__ u16 T[64 * 72];
  int tid = threadIdx.x;
  #pragma unroll
  for (int i = 0; i < 4; i++) {
    int idx = tid + i * 256;
    int r = idx >> 4, ch = idx & 15;
    float4 v = *(const float4*)(d.src + (size_t)(k0 + r) * 3072 + n0 + ch * 4);
    T[(ch*4+0)*72 + r] = f2bf(v.x);
    T[(ch*4+1)*72 + r] = f2bf(v.y);
    T[(ch*4+2)*72 + r] = f2bf(v.z);
    T[(ch*4+3)*72 + r] = f2bf(v.w);
  }
  __syncthreads();
  #pragma unroll
  for (int i = 0; i < 2; i++) {
    int idx = tid + i * 256;
    int r = idx >> 3, ch = idx & 7;
    uint4 v = *(const uint4*)(T + r * 72 + ch * 8);
    *(uint4*)(d.dst + (size_t)(n0 + r) * K + k0 + ch * 8) = v;
  }
}

// ---------------- batched GEMM: per-job C(M,3072) = A(M,K) @ W^T + bias ----------------
// MT x 128 tile, BK=64, 4 waves, global_load_lds staging with XOR-chunk LDS swizzle.
// LDS chunk for (row, kc16B) lives at slot row*8 + (kc ^ (row&7)) -> frag reads are 2-way (free).
struct GJob { const u16* A; const u16* W; const float* bias; void* C; int M; int K; int blk0; int out_f32; };
struct GPack { GJob j[8]; int njobs; };

template<int MT>
__global__ __launch_bounds__(256) void k_gemm(GPack p)
{
  __shared__ u16 As[MT * 64];
  __shared__ u16 Bs[128 * 64];
  int bid = blockIdx.x;
  int ji = 0;
  while (ji + 1 < p.njobs && bid >= p.j[ji+1].blk0) ji++;
  GJob J = p.j[ji];
  int local = bid - J.blk0;
  int m0 = (local / 24) * MT;
  int n0 = (local % 24) * 128;

  int tid = threadIdx.x, w = tid >> 6, lane = tid & 63, l15 = lane & 15, quad = lane >> 4;
  constexpr int MF = MT / 32;                 // m-frags per wave (4 or 2)
  int wm = (w >> 1) * (MT / 2), wn = (w & 1) * 64;
  f32x4 acc[MF][4] = {};

  constexpr int GA = MT * 8 / 256;            // A staging groups (4 or 2)
  const u16* Ag[GA]; const u16* Bg[4];
  #pragma unroll
  for (int i = 0; i < GA; i++) {
    int s = i * 256 + tid;
    int row = s >> 3, kc = (s & 7) ^ (row & 7);
    Ag[i] = J.A + (size_t)(m0 + row) * J.K + kc * 8;
  }
  #pragma unroll
  for (int i = 0; i < 4; i++) {
    int s = i * 256 + tid;
    int row = s >> 3, kc = (s & 7) ^ (row & 7);
    Bg[i] = J.W + (size_t)(n0 + row) * J.K + kc * 8;
  }

  for (int k0 = 0; k0 < J.K; k0 += 64) {
    #pragma unroll
    for (int i = 0; i < GA; i++)
      gload16(Ag[i] + k0, As + (size_t)(i * 256 + w * 64) * 8);
    #pragma unroll
    for (int i = 0; i < 4; i++)
      gload16(Bg[i] + k0, Bs + (size_t)(i * 256 + w * 64) * 8);
    __syncthreads();
    int x7 = l15 & 7;
    #pragma unroll
    for (int ks = 0; ks < 2; ks++) {
      bf16x8 af[MF], bfr[4];
      #pragma unroll
      for (int t = 0; t < MF; t++)
        af[t] = *(const bf16x8*)(As + (wm + t * 16 + l15) * 64 + (((ks * 4 + quad) ^ x7) * 8));
      #pragma unroll
      for (int t = 0; t < 4; t++)
        bfr[t] = *(const bf16x8*)(Bs + (wn + t * 16 + l15) * 64 + (((ks * 4 + quad) ^ x7) * 8));
      #pragma unroll
      for (int mt = 0; mt < MF; mt++)
        #pragma unroll
        for (int nt = 0; nt < 4; nt++)
          acc[mt][nt] = __builtin_amdgcn_mfma_f32_16x16x32_bf16(af[mt], bfr[nt], acc[mt][nt], 0, 0, 0);
    }
    __syncthreads();
  }

  #pragma unroll
  for (int mt = 0; mt < MF; mt++) {
    int row = m0 + wm + mt * 16 + quad * 4;
    #pragma unroll
    for (int nt = 0; nt < 4; nt++) {
      int col = n0 + wn + nt * 16 + l15;
      float bv = J.bias[col];
      #pragma unroll
      for (int r = 0; r < 4; r++) {
        if (row + r < J.M) {
          float v = acc[mt][nt][r] + bv;
          if (J.out_f32) ((float*)J.C)[(size_t)(row + r) * 3072 + col] = v;
          else           ((u16*)J.C)[(size_t)(row + r) * 3072 + col] = f2bf(v);
        }
      }
    }
  }
}

// ---------------- pack Q/K: RMS + RoPE + scale, head-major ----------------
__global__ __launch_bounds__(256) void k_pack_qk(
    const u16* __restrict__ q, const u16* __restrict__ k,
    const u16* __restrict__ eq, const u16* __restrict__ ek,
    const u16* __restrict__ ipk,
    const float* __restrict__ cosr, const float* __restrict__ sinr,
    const float* __restrict__ nq, const float* __restrict__ nk,
    const float* __restrict__ naq, const float* __restrict__ nak,
    const float* __restrict__ nipq, const float* __restrict__ nipk,
    u16* __restrict__ Qf, u16* __restrict__ Kf, u16* __restrict__ Qip, u16* __restrict__ Kip)
{
  int u = blockIdx.x * 4 + (threadIdx.x >> 6);
  int lane = threadIdx.x & 63;
  int d0 = lane * 2;
  if (u < 36864) {
    int t = u / 24, h = u % 24;
    bool txt = t < 512;
    const u16* qrow = txt ? eq + (size_t)t * 3072 : q + (size_t)(t - 512) * 3072;
    const u16* krow = txt ? ek + (size_t)t * 3072 : k + (size_t)(t - 512) * 3072;
    u32 qv = ((const u32*)(qrow + h * 128))[lane];
    u32 kv = ((const u32*)(krow + h * 128))[lane];
    float q0 = bf2f((u16)qv), q1 = bf2f((u16)(qv >> 16));
    float k0 = bf2f((u16)kv), k1 = bf2f((u16)(kv >> 16));
    float sq = q0 * q0 + q1 * q1, sk = k0 * k0 + k1 * k1;
    #pragma unroll
    for (int off = 32; off > 0; off >>= 1) {
      sq += __shfl_xor(sq, off, 64);
      sk += __shfl_xor(sk, off, 64);
    }
    float rq = rsqrtf(sq * (1.0f / 128.0f) + 1e-6f);
    float rk = rsqrtf(sk * (1.0f / 128.0f) + 1e-6f);
    const float* wq = txt ? naq : nq;
    const float* wk = txt ? nak : nk;
    float2 c = ((const float2*)(cosr + (size_t)t * 128))[lane];
    float2 s = ((const float2*)(sinr + (size_t)t * 128))[lane];
    float xq0 = q0 * rq * wq[d0] * QSCALE, xq1 = q1 * rq * wq[d0 + 1] * QSCALE;
    float xk0 = k0 * rk * wk[d0],          xk1 = k1 * rk * wk[d0 + 1];
    u32 oq = (u32)f2bf(xq0 * c.x - xq1 * s.x) | ((u32)f2bf(xq1 * c.y + xq0 * s.y) << 16);
    u32 ok = (u32)f2bf(xk0 * c.x - xk1 * s.x) | ((u32)f2bf(xk1 * c.y + xk0 * s.y) << 16);
    ((u32*)(Qf + ((size_t)h * 1536 + t) * 128))[lane] = oq;
    ((u32*)(Kf + ((size_t)h * 1536 + t) * 128))[lane] = ok;
    if (!txt) {
      float y0 = q0 * rq * nipq[d0] * QSCALE, y1 = q1 * rq * nipq[d0 + 1] * QSCALE;
      u32 oy = (u32)f2bf(y0) | ((u32)f2bf(y1) << 16);
      ((u32*)(Qip + ((size_t)h * 1024 + (t - 512)) * 128))[lane] = oy;
    }
  } else {
    int u2 = u - 36864;
    if (u2 < 384) {
      int h = u2 >> 4, t = u2 & 15;
      u32 v = ((const u32*)(ipk + (size_t)t * 3072 + h * 128))[lane];
      float x0 = bf2f((u16)v), x1 = bf2f((u16)(v >> 16));
      float ss = x0 * x0 + x1 * x1;
      #pragma unroll
      for (int off = 32; off > 0; off >>= 1) ss += __shfl_xor(ss, off, 64);
      float rr = rsqrtf(ss * (1.0f / 128.0f) + 1e-6f);
      u32 o = (u32)f2bf(x0 * rr * nipk[d0]) | ((u32)f2bf(x1 * rr * nipk[d0 + 1]) << 16);
      ((u32*)(Kip + ((size_t)h * 64 + t) * 128))[lane] = o;   // Kip padded to 64 keys
    }
  }
}

// ---------------- pack V transposed: Vt (24,128,1536), Vipt (24,128,64) zero-padded ----------------
__global__ __launch_bounds__(256) void k_pack_v(
    const u16* __restrict__ v, const u16* __restrict__ ev, const u16* __restrict__ ipv,
    u16* __restrict__ Vt, u16* __restrict__ Vipt)
{
  __shared__ u16 T[64 * 72];
  int h = blockIdx.x, y = blockIdx.y, tid = threadIdx.x;
  if (y < 48) {
    int tb = (y % 24) * 64, db = (y / 24) * 64;
    #pragma unroll
    for (int i = 0; i < 2; i++) {
      int idx = tid + i * 256;
      int r = idx >> 3, ch = idx & 7;
      int t = tb + r;
      const u16* src = (t < 512) ? ev + (size_t)t * 3072 : v + (size_t)(t - 512) * 3072;
      uint4 val = *(const uint4*)(src + h * 128 + db + ch * 8);
      u16 tmp[8];
      *(uint4*)tmp = val;
      #pragma unroll
      for (int j = 0; j < 8; j++) T[(ch * 8 + j) * 72 + r] = tmp[j];
    }
    __syncthreads();
    #pragma unroll
    for (int i = 0; i < 2; i++) {
      int idx = tid + i * 256;
      int r = idx >> 3, ch = idx & 7;
      uint4 val = *(const uint4*)(T + r * 72 + ch * 8);
      *(uint4*)(Vt + ((size_t)h * 128 + db + r) * 1536 + tb + ch * 8) = val;
    }
  } else {
    if (tid < 128) {
      #pragma unroll
      for (int t = 0; t < 64; t++) {
        u16 val = 0;
        if (t < 16) val = ipv[(size_t)t * 3072 + h * 128 + tid];
        Vipt[((size_t)h * 128 + tid) * 64 + t] = val;  // zero pad keys 16..63
      }
    }
  }
}

// ---------------- flash attention, transposed-score formulation ----------------
__global__ __launch_bounds__(256) void k_attn(
    const u16* __restrict__ Q, const u16* __restrict__ K, const u16* __restrict__ V,
    const float* __restrict__ addend, void* __restrict__ out,
    int Sq, int Skv, int Skv_valid, int mode)
{
  __shared__ u16 Ks[64 * 128];   // [key][d-chunk swizzled]: chunk' = ch ^ (key&15)
  __shared__ u16 Vs[128 * 64];   // [d][key-chunk swizzled]: chunk' = ch ^ (d&7)
  __shared__ u16 Ps[4 * 16 * 68];
  int tid = threadIdx.x, h = blockIdx.y;
  int w = tid >> 6, lane = tid & 63, l15 = lane & 15, quad = lane >> 4;
  int mb = blockIdx.x * 64 + w * 16;

  bf16x8 aq[4];
  {
    const u16* qp = Q + ((size_t)h * Sq + mb + l15) * 128 + quad * 8;
    #pragma unroll
    for (int c = 0; c < 4; c++) aq[c] = *(const bf16x8*)(qp + c * 32);
  }

  const u16* Kg[4]; const u16* Vg[4];
  #pragma unroll
  for (int i = 0; i < 4; i++) {
    int s = tid + i * 256;
    int key = s >> 4, kc = (s & 15) ^ (key & 15);
    Kg[i] = K + ((size_t)h * Skv + key) * 128 + kc * 8;
    int d = s >> 3, vc = (s & 7) ^ (d & 7);
    Vg[i] = V + ((size_t)h * 128 + d) * Skv + vc * 8;
  }

  f32x4 o[8] = {};
  float m_col = -3.0e38f, l_col = 0.0f;
  u16* myPs = Ps + w * (16 * 68);

  for (int kb = 0; kb < Skv; kb += 64) {
    #pragma unroll
    for (int i = 0; i < 4; i++) {
      gload16(Kg[i] + (size_t)kb * 128, Ks + (i * 256 + w * 64) * 8);
      gload16(Vg[i] + kb,               Vs + (i * 256 + w * 64) * 8);
    }
    __syncthreads();

    f32x4 sc[4];
    #pragma unroll
    for (int mt = 0; mt < 4; mt++) {
      f32x4 a = {0.f, 0.f, 0.f, 0.f};
      int key = mt * 16 + l15;
      #pragma unroll
      for (int c = 0; c < 4; c++) {
        bf16x8 kf = *(const bf16x8*)(Ks + key * 128 + (((c * 4 + quad) ^ l15) * 8));
        a = __builtin_amdgcn_mfma_f32_16x16x32_bf16(kf, aq[c], a, 0, 0, 0);
      }
      sc[mt] = a;
    }
    if (Skv_valid != Skv) {
      #pragma unroll
      for (int mt = 0; mt < 4; mt++)
        #pragma unroll
        for (int r = 0; r < 4; r++)
          if (kb + mt * 16 + quad * 4 + r >= Skv_valid) sc[mt][r] = -1e30f;
    }

    float mx = sc[0][0];
    #pragma unroll
    for (int mt = 0; mt < 4; mt++)
      #pragma unroll
      for (int r = 0; r < 4; r++) mx = fmaxf(mx, sc[mt][r]);
    mx = fmaxf(mx, __shfl_xor(mx, 16, 64));
    mx = fmaxf(mx, __shfl_xor(mx, 32, 64));
    float mn = fmaxf(m_col, mx);
    float alpha = __expf(m_col - mn);
    m_col = mn;

    float sum = 0.f;
    #pragma unroll
    for (int mt = 0; mt < 4; mt++) {
      u16 pk[4];
      #pragma unroll
      for (int r = 0; r < 4; r++) {
        float pp = __expf(sc[mt][r] - mn);
        sum += pp;
        pk[r] = f2bf(pp);
      }
      uint2 pv;
      pv.x = (u32)pk[0] | ((u32)pk[1] << 16);
      pv.y = (u32)pk[2] | ((u32)pk[3] << 16);
      *(uint2*)(myPs + l15 * 68 + mt * 16 + quad * 4) = pv;
    }
    sum += __shfl_xor(sum, 16, 64);
    sum += __shfl_xor(sum, 32, 64);
    l_col = l_col * alpha + sum;

    float ar[4];
    #pragma unroll
    for (int r = 0; r < 4; r++) ar[r] = __shfl(alpha, quad * 4 + r, 64);
    #pragma unroll
    for (int nt = 0; nt < 8; nt++) {
      o[nt][0] *= ar[0]; o[nt][1] *= ar[1]; o[nt][2] *= ar[2]; o[nt][3] *= ar[3];
    }

    __asm__ volatile("s_waitcnt lgkmcnt(0)" ::: "memory");
    #pragma unroll
    for (int kc = 0; kc < 2; kc++) {
      bf16x8 pa = *(const bf16x8*)(myPs + l15 * 68 + kc * 32 + quad * 8);
      #pragma unroll
      for (int nt = 0; nt < 8; nt++) {
        int d = nt * 16 + l15;
        bf16x8 vf = *(const bf16x8*)(Vs + d * 64 + (((kc * 4 + quad) ^ (d & 7)) * 8));
        o[nt] = __builtin_amdgcn_mfma_f32_16x16x32_bf16(pa, vf, o[nt], 0, 0, 0);
      }
    }
    __syncthreads();
  }

  float linv = 1.0f / l_col;
  float lr[4];
  #pragma unroll
  for (int r = 0; r < 4; r++) lr[r] = __shfl(linv, quad * 4 + r, 64);
  #pragma unroll
  for (int r = 0; r < 4; r++) {
    int t = mb + quad * 4 + r;
    size_t base = (size_t)t * 3072 + h * 128 + l15;
    if (mode == 0) {
      float* O = (float*)out;
      #pragma unroll
      for (int nt = 0; nt < 8; nt++) O[base + nt * 16] = o[nt][r] * lr[r];
    } else {
      u16* O = (u16*)out;
      #pragma unroll
      for (int nt = 0; nt < 8; nt++) {
        float vv = o[nt][r] * lr[r];
        if (t >= 512) vv += addend[(size_t)(t - 512) * 3072 + h * 128 + nt * 16 + l15];
        O[base + nt * 16] = f2bf(vv);
      }
    }
  }
}

extern "C" void kernel_launch(void* const* d_in, const int* in_sizes, int n_in,
                              void* d_out, int out_size, void* d_ws, size_t ws_size,
                              hipStream_t stream) {
  const float* hs   = (const float*)d_in[0];
  const float* ehs  = (const float*)d_in[1];
  const float* iph  = (const float*)d_in[2];
  const float* cosr = (const float*)d_in[3];
  const float* sinr = (const float*)d_in[4];
  const float* Wq   = (const float*)d_in[5];  const float* bq   = (const float*)d_in[6];
  const float* Wk   = (const float*)d_in[7];  const float* bk   = (const float*)d_in[8];
  const float* Wv   = (const float*)d_in[9];  const float* bv   = (const float*)d_in[10];
  const float* nq   = (const float*)d_in[11]; const float* nk   = (const float*)d_in[12];
  const float* Waq  = (const float*)d_in[13]; const float* baq  = (const float*)d_in[14];
  const float* Wak  = (const float*)d_in[15]; const float* bak  = (const float*)d_in[16];
  const float* Wav  = (const float*)d_in[17]; const float* bav  = (const float*)d_in[18];
  const float* naq  = (const float*)d_in[19]; const float* nak  = (const float*)d_in[20];
  const float* Wo   = (const float*)d_in[21]; const float* bo   = (const float*)d_in[22];
  const float* Wad  = (const float*)d_in[23]; const float* bad  = (const float*)d_in[24];
  const float* Wkip = (const float*)d_in[25]; const float* bkip = (const float*)d_in[26];
  const float* Wvip = (const float*)d_in[27]; const float* bvip = (const float*)d_in[28];
  const float* nipq = (const float*)d_in[29]; const float* nipk = (const float*)d_in[30];
  (void)in_sizes; (void)n_in; (void)out_size; (void)ws_size;

  char* ws = (char*)d_ws;
  size_t off = 0;
  auto alloc = [&](size_t bytes) { size_t o = off; off += (bytes + 255) & ~(size_t)255; return o; };

  u16* hsb  = (u16*)(ws + alloc((size_t)1024 * 3072 * 2));
  u16* ehsb = (u16*)(ws + alloc((size_t)512 * 3072 * 2));
  u16* ipb  = (u16*)(ws + alloc((size_t)16 * 2048 * 2));
  u16* WT_[10];
  for (int i = 0; i < 10; i++) WT_[i] = (u16*)(ws + alloc((size_t)3072 * (i < 8 ? 3072 : 2048) * 2));
  u16* qb   = (u16*)(ws + alloc((size_t)1024 * 3072 * 2));
  u16* kb_  = (u16*)(ws + alloc((size_t)1024 * 3072 * 2));
  u16* vb   = (u16*)(ws + alloc((size_t)1024 * 3072 * 2));
  u16* eqb  = (u16*)(ws + alloc((size_t)512 * 3072 * 2));
  u16* ekb  = (u16*)(ws + alloc((size_t)512 * 3072 * 2));
  u16* evb  = (u16*)(ws + alloc((size_t)512 * 3072 * 2));
  u16* ipkb = (u16*)(ws + alloc((size_t)16 * 3072 * 2));
  u16* ipvb = (u16*)(ws + alloc((size_t)16 * 3072 * 2));
  u16* Qf   = (u16*)(ws + alloc((size_t)24 * 1536 * 128 * 2));
  u16* Kff  = (u16*)(ws + alloc((size_t)24 * 1536 * 128 * 2));
  u16* Vt   = (u16*)(ws + alloc((size_t)24 * 128 * 1536 * 2));
  u16* Qip  = (u16*)(ws + alloc((size_t)24 * 1024 * 128 * 2));
  u16* Kip  = (u16*)(ws + alloc((size_t)24 * 64 * 128 * 2));
  u16* Vipt = (u16*)(ws + alloc((size_t)24 * 128 * 64 * 2));
  float* ip_out = (float*)(ws + alloc((size_t)1024 * 3072 * 4));
  u16* attnb = (u16*)(ws + alloc((size_t)1536 * 3072 * 2));

  k_conv_acts<<<4640, 256, 0, stream>>>(hs, ehs, iph, hsb, ehsb, ipb);

  WTPack p;
  const float* wsrc[10] = {Wq, Wk, Wv, Waq, Wak, Wav, Wo, Wad, Wkip, Wvip};
  for (int i = 0; i < 10; i++) { p.w[i].src = wsrc[i]; p.w[i].dst = WT_[i]; p.w[i].K = (i < 8 ? 3072 : 2048); }
  k_transp_w<<<dim3(48, 48, 10), 256, 0, stream>>>(p);

  // all 8 projection GEMMs in one dispatch (128-row tiles)
  {
    GPack pp;
    const u16* As_[8]  = {hsb, hsb, hsb, ehsb, ehsb, ehsb, ipb, ipb};
    const u16* Ws_[8]  = {WT_[0], WT_[1], WT_[2], WT_[3], WT_[4], WT_[5], WT_[8], WT_[9]};
    const float* bs_[8] = {bq, bk, bv, baq, bak, bav, bkip, bvip};
    u16* Cs_[8]        = {qb, kb_, vb, eqb, ekb, evb, ipkb, ipvb};
    int Ms_[8] = {1024, 1024, 1024, 512, 512, 512, 16, 16};
    int Ks_[8] = {3072, 3072, 3072, 3072, 3072, 3072, 2048, 2048};
    int blk = 0;
    for (int i = 0; i < 8; i++) {
      pp.j[i].A = As_[i]; pp.j[i].W = Ws_[i]; pp.j[i].bias = bs_[i]; pp.j[i].C = Cs_[i];
      pp.j[i].M = Ms_[i]; pp.j[i].K = Ks_[i]; pp.j[i].blk0 = blk; pp.j[i].out_f32 = 0;
      blk += ((Ms_[i] + 127) / 128) * 24;
    }
    pp.njobs = 8;
    k_gemm<128><<<dim3(blk), 256, 0, stream>>>(pp);  // 912 blocks
  }

  k_pack_qk<<<9312, 256, 0, stream>>>(qb, kb_, eqb, ekb, ipkb, cosr, sinr, nq, nk, naq, nak, nipq, nipk, Qf, Kff, Qip, Kip);
  k_pack_v<<<dim3(24, 49), 256, 0, stream>>>(vb, evb, ipvb, Vt, Vipt);

  // IP attention first (f32), then main attention fuses the add and writes bf16
  k_attn<<<dim3(16, 24), 256, 0, stream>>>(Qip, Kip, Vipt, (const float*)nullptr, ip_out, 1024, 64, 16, 0);
  k_attn<<<dim3(24, 24), 256, 0, stream>>>(Qf, Kff, Vt, ip_out, attnb, 1536, 1536, 1536, 1);

  // output projections: 64-row m-tiles -> 576 blocks for latency hiding
  {
    GPack pp;
    float* out = (float*)d_out;
    pp.j[0].A = attnb + (size_t)512 * 3072; pp.j[0].W = WT_[6]; pp.j[0].bias = bo;
    pp.j[0].C = out; pp.j[0].M = 1024; pp.j[0].K = 3072; pp.j[0].blk0 = 0; pp.j[0].out_f32 = 1;
    pp.j[1].A = attnb; pp.j[1].W = WT_[7]; pp.j[1].bias = bad;
    pp.j[1].C = out + (size_t)1024 * 3072; pp.j[1].M = 512; pp.j[1].K = 3072;
    pp.j[1].blk0 = (1024 / 64) * 24; pp.j[1].out_f32 = 1;
    pp.njobs = 2;
    k_gemm<64><<<dim3((1024 / 64) * 24 + (512 / 64) * 24), 256, 0, stream>>>(pp);
  }
}